// Round 2
// 444.948 us; speedup vs baseline: 1.0282x; 1.0282x over previous
//
#include <hip/hip_runtime.h>
#include <math.h>

typedef __attribute__((ext_vector_type(8))) short short8;
typedef __attribute__((ext_vector_type(4))) float floatx4;

// fp32 -> bf16, round-to-nearest-even, bit pattern in a short
__device__ __forceinline__ short f2bf(float f) {
  union { float f; unsigned u; } v; v.f = f;
  unsigned r = v.u + 0x7fffu + ((v.u >> 16) & 1u);
  return (short)(r >> 16);
}

struct Params {
  const float* fs[5];
  const float* ft[5];
  const float* bias[5];
  const float* mask[5];
  const short8* wp[5];
  float* sums;
};

// ---------------------------------------------------------------------------
// Fused prep kernel: blocks 0..159 prepack adapt_w into bf16 MFMA A-fragment
// order; blocks 160..199 rasterize gt-box masks; block 200 zeroes sums.
// Replaces memset + prepack_w + mask_kernel (3 dispatches -> 1).
// ---------------------------------------------------------------------------
__global__ void prep(const float* __restrict__ w0, const float* __restrict__ w1,
                     const float* __restrict__ w2, const float* __restrict__ w3,
                     const float* __restrict__ w4, short8* __restrict__ wp,
                     const float* __restrict__ gtb, float* __restrict__ mask_base,
                     float* __restrict__ sums) {
  __shared__ int lx[16], ly[16], rx[16], ry[16], dg[16];
  int blk = blockIdx.x;
  if (blk < 160) {
    int id = blk * 256 + threadIdx.x;        // exactly 5*8192 ids
    int lvl = id >> 13;
    int idx = id & 8191;
    const float* W = (lvl == 0) ? w0 : (lvl == 1) ? w1 : (lvl == 2) ? w2 : (lvl == 3) ? w3 : w4;
    int t16 = idx >> 9;
    int kt  = (idx >> 6) & 7;
    int ln  = idx & 63;
    int m = t16 * 16 + (ln & 15);
    int c = kt * 32 + (ln >> 4) * 8;
    const float* s = W + m * 256 + c;
    short8 v;
#pragma unroll
    for (int j = 0; j < 8; j++) v[j] = f2bf(s[j]);
    wp[id] = v;
  } else if (blk < 200) {
    const int szs[5]  = {128, 64, 32, 16, 8};
    const int strd[5] = {8, 16, 32, 64, 128};
    const int offs[5] = {0, 131072, 163840, 172032, 174080};
    int idx = blk - 160;
    int b = idx & 7, lvl = idx >> 3;
    int hw = szs[lvl];
    int P = hw * hw;
    if (threadIdx.x < 16) {
      int n = threadIdx.x;
      const float* bb = gtb + (b * 16 + n) * 4;
      float inv = 1.0f / (float)strd[lvl];   // pow2 stride -> exact
      int qx1 = (int)floorf(bb[0] * inv);
      int qy1 = (int)floorf(bb[1] * inv);
      int qx2 = (int)floorf(bb[2] * inv);
      int qy2 = (int)floorf(bb[3] * inv);
      int wl = hw - 1;
      int a = min(qx1, wl), c = min(qy1, wl), d = min(qx2, wl), e = min(qy2, wl);
      lx[n] = a; ly[n] = c; rx[n] = d; ry[n] = e;
      dg[n] = (a == d) || (c == e);
    }
    __syncthreads();
    float* mp = mask_base + offs[lvl] + b * P;
    for (int p = threadIdx.x; p < P; p += blockDim.x) {
      int y = p / hw, x = p - y * hw;
      bool any = false;
#pragma unroll
      for (int n = 0; n < 16; n++) {
        bool cov = dg[n] ? (y == ly[n] && x == lx[n])
                         : (y >= ly[n] && y < ry[n] && x >= lx[n] && x < rx[n]);
        any = any || cov;
      }
      mp[p] = any ? 1.0f : 0.0f;
    }
  } else {
    if (threadIdx.x < 16) sums[threadIdx.x] = 0.f;   // 64 B of sums (10 used)
  }
}

// ---------------------------------------------------------------------------
// Fused GEMM + masked loss. Block = 256 threads = 4 waves; block tile
// 256(o) x 64(p).
//   * Cooperative LDS staging of the shared B-tile (bf16): each thread
//     gathers ONE 8-element fragment, converts, ds_write_b128; waves then
//     ds_read_b128 fragments. 4x fewer global gathers + 4x fewer cvts than
//     per-wave private gathering, and the fs tile is pulled from L2 once.
//   * 2-deep pipeline: gathers for kt+2 and A-frags for kt+1 issued before
//     the MFMAs of kt; barriers are raw s_barrier + lgkmcnt(0) only, so the
//     in-flight global loads are NOT drained at the barrier (no vmcnt(0)
//     in the K-loop).
// LDS buffer layout: lbuf[buf][p][quad] : short8 = LB[p][klocal=quad*8+j]
// (bank-balanced for both the b128 writes and reads).
// ---------------------------------------------------------------------------
template<int PL2, int LVL>
__device__ __forceinline__ void level_body(const Params& pr, int rem, float* red,
                                           short8 (*lbuf)[64][4]) {
  constexpr int P = 64 << PL2;
  const int tid  = threadIdx.x;
  const int lane = tid & 63;
  const int wave = tid >> 6;
  const int quad = lane >> 4, l15 = lane & 15;
  const int bz = rem >> PL2;
  const int p0 = (rem & ((1 << PL2) - 1)) << 6;

  const float*  fsb   = pr.fs[LVL]  + (size_t)bz * 256 * P;
  const float*  ftb   = pr.ft[LVL]  + (size_t)bz * 256 * P;
  const short8* wpb   = pr.wp[LVL]  + lane;                 // + ((wave*4+mi)*8+kt)*64
  const float*  maskb = pr.mask[LVL] + (size_t)bz * P;
  const float*  biasp = pr.bias[LVL];

  // this thread's gather column/rows: col p0+wave*16+l15, rows kt*32+quad*8+j
  const float* gbase = fsb + (size_t)quad * 8 * P + (p0 + wave * 16 + l15);

  floatx4 acc[4][4];
#pragma unroll
  for (int i = 0; i < 4; i++)
#pragma unroll
    for (int j = 0; j < 4; j++) acc[i][j] = (floatx4){0.f, 0.f, 0.f, 0.f};

  float  g[2][8];     // raw f32 gathers, 2 K-steps deep
  short8 af[2][4];    // packed A fragments, 1 K-step ahead

  // ---- prologue: issue g(0), af(0), g(1); stage kt=0 into buf0 ----
#pragma unroll
  for (int j = 0; j < 8; j++) g[0][j] = gbase[(size_t)(0 * 32 + j) * P];
#pragma unroll
  for (int mi = 0; mi < 4; mi++) af[0][mi] = wpb[((wave * 4 + mi) * 8 + 0) * 64];
#pragma unroll
  for (int j = 0; j < 8; j++) g[1][j] = gbase[(size_t)(1 * 32 + j) * P];
  {
    short8 v;
#pragma unroll
    for (int j = 0; j < 8; j++) v[j] = f2bf(g[0][j]);
    lbuf[0][wave * 16 + l15][quad] = v;
  }
  asm volatile("s_waitcnt lgkmcnt(0)" ::: "memory");
  __builtin_amdgcn_s_barrier();
  asm volatile("" ::: "memory");

  // ---- K loop: 8 steps of K=32, fully unrolled ----
#pragma unroll
  for (int kt = 0; kt < 8; kt++) {
    const int cur = kt & 1;
    float  gn[8];
    short8 afn[4];
    if (kt + 2 < 8) {           // prefetch raw fs for kt+2
#pragma unroll
      for (int j = 0; j < 8; j++) gn[j] = gbase[(size_t)((kt + 2) * 32 + j) * P];
    }
    if (kt + 1 < 8) {           // prefetch A fragments for kt+1 (L2-hot)
#pragma unroll
      for (int mi = 0; mi < 4; mi++)
        afn[mi] = wpb[((wave * 4 + mi) * 8 + (kt + 1)) * 64];
    }

    short8 bf[4];
#pragma unroll
    for (int ni = 0; ni < 4; ni++) bf[ni] = lbuf[cur][ni * 16 + l15][quad];
#pragma unroll
    for (int mi = 0; mi < 4; mi++)
#pragma unroll
      for (int ni = 0; ni < 4; ni++)
        acc[mi][ni] = __builtin_amdgcn_mfma_f32_16x16x32_bf16(af[cur][mi], bf[ni], acc[mi][ni], 0, 0, 0);

    if (kt + 1 < 8) {           // convert g(kt+1), stage into the other buffer
      short8 v;
#pragma unroll
      for (int j = 0; j < 8; j++) v[j] = f2bf(g[1 - cur][j]);
      lbuf[1 - cur][wave * 16 + l15][quad] = v;
#pragma unroll
      for (int mi = 0; mi < 4; mi++) af[1 - cur][mi] = afn[mi];
    }
    if (kt + 2 < 8) {
#pragma unroll
      for (int j = 0; j < 8; j++) g[cur][j] = gn[j];
    }
    if (kt + 1 < 8) {
      asm volatile("s_waitcnt lgkmcnt(0)" ::: "memory");   // drain LDS only;
      __builtin_amdgcn_s_barrier();                        // global prefetch
      asm volatile("" ::: "memory");                       // stays in flight
    }
  }

  // ---- epilogue: diff^2 vs feat_t, masked accumulate ----
  float sgt = 0.f, sbg = 0.f;
#pragma unroll
  for (int ni = 0; ni < 4; ni++) {
    int p = p0 + ni * 16 + l15;
    float mk = maskb[p];
#pragma unroll
    for (int mi = 0; mi < 4; mi++) {
      int ob = wave * 64 + mi * 16 + quad * 4;
      const float* ftp = ftb + (size_t)ob * P + p;
#pragma unroll
      for (int r = 0; r < 4; r++) {
        float ad = acc[mi][ni][r] + biasp[ob + r];
        float tv = ftp[(size_t)r * P];
        float d = tv - ad;
        float sq = d * d;
        sgt += sq * mk;
        sbg += sq - sq * mk;
      }
    }
  }
#pragma unroll
  for (int off = 32; off > 0; off >>= 1) {
    sgt += __shfl_down(sgt, off);
    sbg += __shfl_down(sbg, off);
  }
  if (lane == 0) { red[wave * 2] = sgt; red[wave * 2 + 1] = sbg; }
  __syncthreads();
  if (tid == 0) {
    atomicAdd(&pr.sums[LVL * 2 + 0], red[0] + red[2] + red[4] + red[6]);
    atomicAdd(&pr.sums[LVL * 2 + 1], red[1] + red[3] + red[5] + red[7]);
  }
}

// block-id ranges (x8 batch, p-tiles of 64): L0 [0,2048) L1 [2048,2560)
// L2 [2560,2688) L3 [2688,2720) L4 [2720,2728)
__global__ __launch_bounds__(256, 2) void gemm_loss_all(Params pr) {
  __shared__ short8 lbuf[2][64][4];   // 8 KiB double-buffered B tile
  __shared__ float red[8];
  int id = blockIdx.x;
  if (id < 2048)      level_body<8, 0>(pr, id,        red, lbuf);
  else if (id < 2560) level_body<6, 1>(pr, id - 2048, red, lbuf);
  else if (id < 2688) level_body<4, 2>(pr, id - 2560, red, lbuf);
  else if (id < 2720) level_body<2, 3>(pr, id - 2688, red, lbuf);
  else                level_body<0, 4>(pr, id - 2720, red, lbuf);
}

__global__ void finalize(const float* __restrict__ sums, float* __restrict__ out) {
  if (threadIdx.x == 0 && blockIdx.x == 0) {
    float L = 0.f;
#pragma unroll
    for (int i = 0; i < 5; i++)
      L += 0.004f * sqrtf(sums[2 * i] + 1e-8f) + 0.0002f * sqrtf(sums[2 * i + 1] + 1e-8f);
    out[0] = L;
  }
}

extern "C" void kernel_launch(void* const* d_in, const int* in_sizes, int n_in,
                              void* d_out, int out_size, void* d_ws, size_t ws_size,
                              hipStream_t stream) {
  (void)in_sizes; (void)n_in; (void)out_size; (void)ws_size;
  const float* fs[5]; const float* ftp[5]; const float* aw[5]; const float* ab[5];
  for (int i = 0; i < 5; i++) {
    fs[i]  = (const float*)d_in[4 * i + 0];
    ftp[i] = (const float*)d_in[4 * i + 1];
    aw[i]  = (const float*)d_in[4 * i + 2];
    ab[i]  = (const float*)d_in[4 * i + 3];
  }
  const float* gtb = (const float*)d_in[20];
  float* out = (float*)d_out;
  char* ws = (char*)d_ws;

  float*  sums  = (float*)ws;                    // 16 floats (10 used)
  float*  masks = (float*)(ws + 64);             // 174592 floats
  short8* wp    = (short8*)(ws + 64 + 698368);   // 5 * 8192 short8, 16B aligned

  prep<<<201, 256, 0, stream>>>(aw[0], aw[1], aw[2], aw[3], aw[4], wp, gtb, masks, sums);

  const int moff[5] = {0, 131072, 163840, 172032, 174080};
  Params pr;
  for (int l = 0; l < 5; l++) {
    pr.fs[l]   = fs[l];
    pr.ft[l]   = ftp[l];
    pr.bias[l] = ab[l];
    pr.mask[l] = masks + moff[l];
    pr.wp[l]   = wp + l * 8192;
  }
  pr.sums = sums;

  gemm_loss_all<<<2728, 256, 0, stream>>>(pr);
  finalize<<<1, 64, 0, stream>>>(sums, out);
}